// Round 1
// baseline (1338.286 us; speedup 1.0000x reference)
//
#include <hip/hip_runtime.h>
#include <math.h>

namespace {

constexpr int B_ = 8;
constexpr int C_ = 256;
constexpr int N_ = 4096;
constexpr int D_ = 8;

constexpr int TM = 64;   // m-rows per attn block
constexpr int TN = 32;   // n-chunk per phase-2 iteration
constexpr float LOG2E = 1.4426950408889634f;

// q/k projection: one thread per n, loop over C with wave-uniform weight s_loads.
__global__ __launch_bounds__(256) void proj_qk_kernel(
    const float* __restrict__ x,
    const float* __restrict__ wq, const float* __restrict__ bq,
    const float* __restrict__ wk, const float* __restrict__ bk,
    float* __restrict__ q, float* __restrict__ k)
{
  const int b = blockIdx.y;
  const int n = blockIdx.x * 256 + threadIdx.x;
  float aq[D_], ak[D_];
  #pragma unroll
  for (int d = 0; d < D_; ++d) { aq[d] = bq[d]; ak[d] = bk[d]; }
  const float* xb = x + (size_t)b * C_ * N_ + n;
  for (int c = 0; c < C_; ++c) {
    const float xv = xb[(size_t)c * N_];
    #pragma unroll
    for (int d = 0; d < D_; ++d) {
      aq[d] = fmaf(wq[d * C_ + c], xv, aq[d]);
      ak[d] = fmaf(wk[d * C_ + c], xv, ak[d]);
    }
  }
  #pragma unroll
  for (int d = 0; d < D_; ++d) {
    q[((size_t)b * D_ + d) * N_ + n] = aq[d];
    k[((size_t)b * D_ + d) * N_ + n] = ak[d];
  }
}

// v projection: block = (256 n) x (64 out channels); weights via uniform s_loads.
__global__ __launch_bounds__(256) void proj_v_kernel(
    const float* __restrict__ x,
    const float* __restrict__ wv, const float* __restrict__ bv,
    float* __restrict__ v)
{
  const int b = blockIdx.z;
  const int o0 = blockIdx.y * 64;
  const int n = blockIdx.x * 256 + threadIdx.x;
  float acc[64];
  #pragma unroll
  for (int o = 0; o < 64; ++o) acc[o] = bv[o0 + o];
  const float* xb = x + (size_t)b * C_ * N_ + n;
  for (int c = 0; c < C_; ++c) {
    const float xv = xb[(size_t)c * N_];
    const float* wr = wv + (size_t)o0 * C_ + c;
    #pragma unroll
    for (int o = 0; o < 64; ++o) acc[o] = fmaf(wr[o * C_], xv, acc[o]);
  }
  #pragma unroll
  for (int o = 0; o < 64; ++o) v[((size_t)b * C_ + o0 + o) * N_ + n] = acc[o];
}

// Fused flash-style attention: block handles (batch b, 64 m-rows).
// Phase 1: two-pass softmax stats (max, sumexp) with S recomputed from q regs.
// Phase 2: per 32-n chunk: stage V-tile + P-tile in LDS, accumulate O in regs.
__global__ __launch_bounds__(256) void attn_kernel(
    const float* __restrict__ q, const float* __restrict__ k,
    const float* __restrict__ v, const float* __restrict__ x,
    const float* __restrict__ gamma, float* __restrict__ out)
{
  __shared__ float qs[D_][TM];
  __shared__ float Pt[4][TN][17];   // [wave][j][r], stride 17: bijective bank map
  __shared__ float vt[TN][C_ + 1];  // [j][c], stride 257: (j+c)%32 -> 2-way (free)

  const int b = blockIdx.y;
  const int m0 = blockIdx.x * TM;
  const int tid = threadIdx.x;
  const int w = tid >> 6;       // wave 0..3 -> rows w*16 .. w*16+15
  const int l = tid & 63;
  const int jl = l & 31;        // n-sub-column within half-wave
  const int half = l >> 5;      // half 0: rows +0..7, half 1: rows +8..15

  for (int idx = tid; idx < D_ * TM; idx += 256) {
    const int d = idx >> 6, m = idx & 63;
    qs[d][m] = q[((size_t)b * D_ + d) * N_ + m0 + m];
  }
  __syncthreads();

  // this lane's 8 rows: m = m0 + w*16 + half*8 + rr
  float qr[8][8];
  #pragma unroll
  for (int rr = 0; rr < 8; ++rr)
    #pragma unroll
    for (int d = 0; d < D_; ++d)
      qr[rr][d] = qs[d][w * 16 + half * 8 + rr];

  const float* kb = k + (size_t)b * D_ * N_;

  // ---- pass A: row max ----
  float rmax[8];
  #pragma unroll
  for (int rr = 0; rr < 8; ++rr) rmax[rr] = -3.0e38f;
  for (int t = 0; t < N_ / 32; ++t) {
    const int n = t * 32 + jl;
    float kd[D_];
    #pragma unroll
    for (int d = 0; d < D_; ++d) kd[d] = kb[(size_t)d * N_ + n];
    #pragma unroll
    for (int rr = 0; rr < 8; ++rr) {
      float s = qr[rr][0] * kd[0];
      #pragma unroll
      for (int d = 1; d < D_; ++d) s = fmaf(qr[rr][d], kd[d], s);
      rmax[rr] = fmaxf(rmax[rr], s);
    }
  }
  #pragma unroll
  for (int rr = 0; rr < 8; ++rr) {
    float m = rmax[rr];
    #pragma unroll
    for (int off = 16; off >= 1; off >>= 1) m = fmaxf(m, __shfl_xor(m, off));
    rmax[rr] = m;   // reduced over the 32-lane half (rows are per-half)
  }

  // ---- pass B: sum exp ----
  float rsum[8];
  #pragma unroll
  for (int rr = 0; rr < 8; ++rr) rsum[rr] = 0.f;
  for (int t = 0; t < N_ / 32; ++t) {
    const int n = t * 32 + jl;
    float kd[D_];
    #pragma unroll
    for (int d = 0; d < D_; ++d) kd[d] = kb[(size_t)d * N_ + n];
    #pragma unroll
    for (int rr = 0; rr < 8; ++rr) {
      float s = qr[rr][0] * kd[0];
      #pragma unroll
      for (int d = 1; d < D_; ++d) s = fmaf(qr[rr][d], kd[d], s);
      rsum[rr] += exp2f((s - rmax[rr]) * LOG2E);
    }
  }
  #pragma unroll
  for (int rr = 0; rr < 8; ++rr) {
    float ss = rsum[rr];
    #pragma unroll
    for (int off = 16; off >= 1; off >>= 1) ss += __shfl_xor(ss, off);
    rsum[rr] = ss;
  }

  float nb[8], rinv[8];
  #pragma unroll
  for (int rr = 0; rr < 8; ++rr) {
    nb[rr] = -rmax[rr] * LOG2E;
    rinv[rr] = 1.0f / rsum[rr];
  }

  // ---- phase 2: O[c][r] accumulation ----
  float Oacc[4][16];  // lane owns c = l + 64*cq, rows r = 0..15 of this wave
  #pragma unroll
  for (int cq = 0; cq < 4; ++cq)
    #pragma unroll
    for (int r = 0; r < 16; ++r) Oacc[cq][r] = 0.f;

  const float* vb = v + (size_t)b * C_ * N_;

  for (int nc = 0; nc < N_ / TN; ++nc) {
    const int n0 = nc * TN;
    __syncthreads();   // previous vt/Pt fully consumed
    // stage v tile transposed: vt[j][c]
    #pragma unroll
    for (int i = 0; i < 8; ++i) {
      const int idx4 = tid + 256 * i;        // 0..2047 float4s
      const int j4 = (idx4 & 7) * 4;
      const int c = idx4 >> 3;
      const float4 vv = *reinterpret_cast<const float4*>(&vb[(size_t)c * N_ + n0 + j4]);
      vt[j4 + 0][c] = vv.x;
      vt[j4 + 1][c] = vv.y;
      vt[j4 + 2][c] = vv.z;
      vt[j4 + 3][c] = vv.w;
    }
    // produce P for this wave's 16 rows at 32 columns (lane: col jl, 8 rows)
    {
      const int n = n0 + jl;
      float kd[D_];
      #pragma unroll
      for (int d = 0; d < D_; ++d) kd[d] = kb[(size_t)d * N_ + n];
      #pragma unroll
      for (int rr = 0; rr < 8; ++rr) {
        float s = qr[rr][0] * kd[0];
        #pragma unroll
        for (int d = 1; d < D_; ++d) s = fmaf(qr[rr][d], kd[d], s);
        Pt[w][jl][half * 8 + rr] = exp2f(fmaf(s, LOG2E, nb[rr])) * rinv[rr];
      }
    }
    __syncthreads();
    // consume: 64 FMA per 20 LDS b32 reads -> VALU-bound
    for (int j = 0; j < TN; ++j) {
      float vv[4];
      #pragma unroll
      for (int cq = 0; cq < 4; ++cq) vv[cq] = vt[j][l + 64 * cq];
      #pragma unroll
      for (int r = 0; r < 16; ++r) {
        const float p = Pt[w][j][r];
        #pragma unroll
        for (int cq = 0; cq < 4; ++cq) Oacc[cq][r] = fmaf(p, vv[cq], Oacc[cq][r]);
      }
    }
  }

  // ---- epilogue: out = gamma * O + x ----
  const float g = gamma[0];
  #pragma unroll
  for (int cq = 0; cq < 4; ++cq) {
    const int c = l + 64 * cq;
    const size_t base = ((size_t)b * C_ + c) * N_ + m0 + w * 16;
    #pragma unroll
    for (int rg = 0; rg < 4; ++rg) {
      const float4 xv = *reinterpret_cast<const float4*>(&x[base + rg * 4]);
      float4 o;
      o.x = fmaf(g, Oacc[cq][rg * 4 + 0], xv.x);
      o.y = fmaf(g, Oacc[cq][rg * 4 + 1], xv.y);
      o.z = fmaf(g, Oacc[cq][rg * 4 + 2], xv.z);
      o.w = fmaf(g, Oacc[cq][rg * 4 + 3], xv.w);
      *reinterpret_cast<float4*>(&out[base + rg * 4]) = o;
    }
  }
}

}  // namespace

extern "C" void kernel_launch(void* const* d_in, const int* in_sizes, int n_in,
                              void* d_out, int out_size, void* d_ws, size_t ws_size,
                              hipStream_t stream) {
  const float* x     = (const float*)d_in[0];
  const float* wq    = (const float*)d_in[1];
  const float* bq    = (const float*)d_in[2];
  const float* wk    = (const float*)d_in[3];
  const float* bk    = (const float*)d_in[4];
  const float* wv    = (const float*)d_in[5];
  const float* bv    = (const float*)d_in[6];
  const float* gamma = (const float*)d_in[7];
  float* out = (float*)d_out;

  // workspace layout: q (1 MB) | k (1 MB) | v (32 MB)  => ~34 MB needed
  float* q = (float*)d_ws;
  float* k = q + (size_t)B_ * D_ * N_;
  float* v = k + (size_t)B_ * D_ * N_;

  proj_qk_kernel<<<dim3(N_ / 256, B_), 256, 0, stream>>>(x, wq, bq, wk, bk, q, k);
  proj_v_kernel<<<dim3(N_ / 256, C_ / 64, B_), 256, 0, stream>>>(x, wv, bv, v);
  attn_kernel<<<dim3(N_ / TM, B_), 256, 0, stream>>>(q, k, v, x, gamma, out);
}

// Round 2
// 460.492 us; speedup vs baseline: 2.9062x; 2.9062x over previous
//
#include <hip/hip_runtime.h>
#include <math.h>

namespace {

constexpr int B_ = 8;
constexpr int C_ = 256;
constexpr int N_ = 4096;
constexpr int D_ = 8;

constexpr int TM = 64;   // m-rows per attn block
constexpr int TN = 64;   // n-chunk per iteration
constexpr float LOG2E = 1.4426950408889634f;

typedef __attribute__((ext_vector_type(8))) short short8;    // 8 bf16 (4 VGPRs)
typedef __attribute__((ext_vector_type(16))) float float16;  // 16 fp32 acc

__device__ inline unsigned short f2bf(float f) {
  unsigned u = __float_as_uint(f);
  u += 0x7FFFu + ((u >> 16) & 1u);   // RNE
  return (unsigned short)(u >> 16);
}

__device__ inline float uniform_f(float f) {
  return __int_as_float(__builtin_amdgcn_readfirstlane(__float_as_int(f)));
}

// q/k projection: one thread per n, loop over C with wave-uniform weight s_loads.
__global__ __launch_bounds__(256) void proj_qk_kernel(
    const float* __restrict__ x,
    const float* __restrict__ wq, const float* __restrict__ bq,
    const float* __restrict__ wk, const float* __restrict__ bk,
    float* __restrict__ q, float* __restrict__ k)
{
  const int b = blockIdx.y;
  const int n = blockIdx.x * 256 + threadIdx.x;
  float aq[D_], ak[D_];
  #pragma unroll
  for (int d = 0; d < D_; ++d) { aq[d] = bq[d]; ak[d] = bk[d]; }
  const float* xb = x + (size_t)b * C_ * N_ + n;
  for (int c = 0; c < C_; ++c) {
    const float xv = xb[(size_t)c * N_];
    #pragma unroll
    for (int d = 0; d < D_; ++d) {
      aq[d] = fmaf(wq[d * C_ + c], xv, aq[d]);
      ak[d] = fmaf(wk[d * C_ + c], xv, ak[d]);
    }
  }
  #pragma unroll
  for (int d = 0; d < D_; ++d) {
    q[((size_t)b * D_ + d) * N_ + n] = aq[d];
    k[((size_t)b * D_ + d) * N_ + n] = ak[d];
  }
}

// v projection -> bf16 output. 32 out-channels per block for occupancy.
__global__ __launch_bounds__(256) void proj_v_kernel(
    const float* __restrict__ x,
    const float* __restrict__ wv, const float* __restrict__ bv,
    unsigned short* __restrict__ v)
{
  const int b = blockIdx.z;
  const int o0 = blockIdx.y * 32;
  const int n = blockIdx.x * 256 + threadIdx.x;
  float acc[32];
  #pragma unroll
  for (int o = 0; o < 32; ++o) acc[o] = bv[o0 + o];
  const float* xb = x + (size_t)b * C_ * N_ + n;
  for (int c = 0; c < C_; ++c) {
    const float xv = xb[(size_t)c * N_];
    const float* wr = wv + (size_t)o0 * C_ + c;
    #pragma unroll
    for (int o = 0; o < 32; ++o) acc[o] = fmaf(wr[o * C_], xv, acc[o]);
  }
  #pragma unroll
  for (int o = 0; o < 32; ++o)
    v[((size_t)b * C_ + o0 + o) * N_ + n] = f2bf(acc[o]);
}

// Fused attention, single phase, MFMA P.V:
//  - per chunk of 64 n: compute P (unnormalized exp(q.k)) in fp32, write bf16
//    to double-buffered LDS tile; accumulate row-sums in registers.
//  - A-frags (V, bf16) read straight from global (L2, XCD-affine by batch).
//  - D[c][m] += A(V[c][n]) . B(P[m][n]) via mfma_f32_32x32x16_bf16.
//  - epilogue: out = (gamma/rowsum) * D + x.
__global__ __launch_bounds__(512, 4) void attn_kernel(
    const float* __restrict__ q, const float* __restrict__ k,
    const unsigned short* __restrict__ v, const float* __restrict__ x,
    const float* __restrict__ gamma, float* __restrict__ out)
{
  __shared__ float qs[TM][D_];
  __shared__ __align__(16) unsigned short ps[2][TM][TN + 8];  // row stride 144B (16B mult)
  __shared__ float rs[TM];

  const int b = blockIdx.x;          // batch -> XCD (flat id mod 8 == b)
  const int m0 = blockIdx.y * TM;
  const int tid = threadIdx.x;
  const int w = tid >> 6;            // wave 0..7
  const int l = tid & 63;
  const int l31 = l & 31;
  const int lh = l >> 5;             // k-group half within frags

  // stage q[64 m][8 d]
  qs[tid >> 3][tid & 7] = q[((size_t)b * D_ + (tid & 7)) * N_ + m0 + (tid >> 3)];
  __syncthreads();

  // wave w owns P rows w*8..w*8+7 -> q in SGPRs
  float qr[8][8];
  #pragma unroll
  for (int rr = 0; rr < 8; ++rr)
    #pragma unroll
    for (int d = 0; d < D_; ++d)
      qr[rr][d] = uniform_f(qs[w * 8 + rr][d]);

  const float* kb = k + (size_t)b * D_ * N_;
  // wave w owns c-range [32w, 32w+32); lane row c = 32w + l31
  const unsigned short* vrow = v + ((size_t)b * C_ + w * 32 + l31) * N_;

  float16 acc[2];
  #pragma unroll
  for (int mt = 0; mt < 2; ++mt)
    #pragma unroll
    for (int r = 0; r < 16; ++r) acc[mt][r] = 0.f;
  float rsum[8];
  #pragma unroll
  for (int rr = 0; rr < 8; ++rr) rsum[rr] = 0.f;

  for (int nc = 0; nc < N_ / TN; ++nc) {
    const int n0 = nc * TN;
    // A-frags (V) from global: lane: c = 32w+l31, n = n0 + g*16 + lh*8 .. +8
    short8 af[4];
    #pragma unroll
    for (int g = 0; g < 4; ++g)
      af[g] = *reinterpret_cast<const short8*>(vrow + n0 + g * 16 + lh * 8);

    // P compute: lane covers col n = n0 + l for this wave's 8 rows
    const int n = n0 + l;
    float kd[D_];
    #pragma unroll
    for (int d = 0; d < D_; ++d) kd[d] = kb[(size_t)d * N_ + n];
    unsigned short pv[8];
    #pragma unroll
    for (int rr = 0; rr < 8; ++rr) {
      float s = qr[rr][0] * kd[0];
      #pragma unroll
      for (int d = 1; d < D_; ++d) s = fmaf(qr[rr][d], kd[d], s);
      const float e = exp2f(s * LOG2E);   // unnormalized, no max-subtract
      rsum[rr] += e;
      pv[rr] = f2bf(e);
    }
    const int buf = nc & 1;
    #pragma unroll
    for (int rr = 0; rr < 8; ++rr) ps[buf][w * 8 + rr][l] = pv[rr];

    __syncthreads();   // P visible; WAR across chunks covered by double buffer

    #pragma unroll
    for (int g = 0; g < 4; ++g) {
      const short8 b0 = *reinterpret_cast<const short8*>(&ps[buf][l31][g * 16 + lh * 8]);
      const short8 b1 = *reinterpret_cast<const short8*>(&ps[buf][32 + l31][g * 16 + lh * 8]);
      acc[0] = __builtin_amdgcn_mfma_f32_32x32x16_bf16(af[g], b0, acc[0], 0, 0, 0);
      acc[1] = __builtin_amdgcn_mfma_f32_32x32x16_bf16(af[g], b1, acc[1], 0, 0, 0);
    }
  }

  // row-sum reduce across lanes (each lane holds partial over its n-class)
  #pragma unroll
  for (int rr = 0; rr < 8; ++rr) {
    float ssum = rsum[rr];
    #pragma unroll
    for (int off = 32; off >= 1; off >>= 1) ssum += __shfl_xor(ssum, off);
    rsum[rr] = ssum;
  }
  if (l == 0) {
    #pragma unroll
    for (int rr = 0; rr < 8; ++rr) rs[w * 8 + rr] = rsum[rr];
  }
  __syncthreads();

  // epilogue: out[c][m] = gamma/rowsum[m] * acc + x
  const float g0 = gamma[0];
  #pragma unroll
  for (int mt = 0; mt < 2; ++mt) {
    const int mloc = mt * 32 + l31;
    const float t = g0 / rs[mloc];
    #pragma unroll
    for (int r = 0; r < 16; ++r) {
      const int c = w * 32 + (r & 3) + 8 * (r >> 2) + 4 * lh;
      const size_t idx = ((size_t)b * C_ + c) * N_ + m0 + mloc;
      out[idx] = fmaf(acc[mt][r], t, x[idx]);
    }
  }
}

}  // namespace

extern "C" void kernel_launch(void* const* d_in, const int* in_sizes, int n_in,
                              void* d_out, int out_size, void* d_ws, size_t ws_size,
                              hipStream_t stream) {
  const float* x     = (const float*)d_in[0];
  const float* wq    = (const float*)d_in[1];
  const float* bq    = (const float*)d_in[2];
  const float* wk    = (const float*)d_in[3];
  const float* bk    = (const float*)d_in[4];
  const float* wv    = (const float*)d_in[5];
  const float* bv    = (const float*)d_in[6];
  const float* gamma = (const float*)d_in[7];
  float* out = (float*)d_out;

  // ws: q (1 MB) | k (1 MB) | v bf16 (16 MB)
  float* q = (float*)d_ws;
  float* k = q + (size_t)B_ * D_ * N_;
  unsigned short* v = (unsigned short*)(k + (size_t)B_ * D_ * N_);

  proj_qk_kernel<<<dim3(N_ / 256, B_), 256, 0, stream>>>(x, wq, bq, wk, bk, q, k);
  proj_v_kernel<<<dim3(N_ / 256, C_ / 32, B_), 256, 0, stream>>>(x, wv, bv, v);
  attn_kernel<<<dim3(B_, N_ / TM), 512, 0, stream>>>(q, k, v, x, gamma, out);
}

// Round 3
// 311.745 us; speedup vs baseline: 4.2929x; 1.4771x over previous
//
#include <hip/hip_runtime.h>
#include <math.h>

namespace {

constexpr int B_ = 8;
constexpr int C_ = 256;
constexpr int N_ = 4096;
constexpr int D_ = 8;

constexpr int TM = 64;    // m-rows per attn block
constexpr int TN = 128;   // n-chunk per iteration
constexpr int PSTRIDE = 136;  // ps row stride in bf16 (16B-aligned, 4-way ok)
constexpr float LOG2E = 1.4426950408889634f;

typedef __attribute__((ext_vector_type(8))) short short8;    // 8 bf16
typedef __attribute__((ext_vector_type(16))) float float16;  // 16 fp32 acc

__device__ inline unsigned short f2bf(float f) {
  unsigned u = __float_as_uint(f);
  u += 0x7FFFu + ((u >> 16) & 1u);   // RNE
  return (unsigned short)(u >> 16);
}
__device__ inline float bf2f(unsigned short h) {
  return __uint_as_float(((unsigned)h) << 16);
}

// ---- wv -> bf16 ----
__global__ __launch_bounds__(256) void prep_kernel(
    const float* __restrict__ wv, unsigned short* __restrict__ wv_bf) {
  const int i = blockIdx.x * 1024 + threadIdx.x;
  #pragma unroll
  for (int j = 0; j < 4; ++j) wv_bf[i + 256 * j] = f2bf(wv[i + 256 * j]);
}

// ---- q/k projection -> transposed hi/lo bf16 layouts ----
// q_t[n][0..7]=bf16(q*log2e) hi, [8..15]=lo ; k_th[n][0..7]=k hi ; k_tl = lo
__global__ __launch_bounds__(256) void proj_qk_kernel(
    const float* __restrict__ x,
    const float* __restrict__ wq, const float* __restrict__ bq,
    const float* __restrict__ wk, const float* __restrict__ bk,
    unsigned short* __restrict__ q_t, unsigned short* __restrict__ k_th,
    unsigned short* __restrict__ k_tl)
{
  __shared__ float red[4][16][64];
  const int b = blockIdx.y;
  const int n0 = blockIdx.x * 64;
  const int tid = threadIdx.x;
  const int w = tid >> 6, l = tid & 63;

  float a[16];
  #pragma unroll
  for (int d = 0; d < 16; ++d) a[d] = 0.f;
  const float* xb = x + (size_t)b * C_ * N_ + n0 + l;
  for (int i = 0; i < 64; ++i) {
    const int c = w * 64 + i;
    const float xv = xb[(size_t)c * N_];
    #pragma unroll
    for (int d = 0; d < 8; ++d) {
      a[d]     = fmaf(wq[d * C_ + c], xv, a[d]);
      a[8 + d] = fmaf(wk[d * C_ + c], xv, a[8 + d]);
    }
  }
  #pragma unroll
  for (int d = 0; d < 16; ++d) red[w][d][l] = a[d];
  __syncthreads();

  #pragma unroll
  for (int p = 0; p < 4; ++p) {
    const int idx = tid + 256 * p;
    const int d = idx >> 6, n = idx & 63;
    const float v = red[0][d][n] + red[1][d][n] + red[2][d][n] + red[3][d][n];
    const size_t gn = (size_t)b * N_ + n0 + n;
    if (d < 8) {
      const float qs = (v + bq[d]) * LOG2E;   // pre-scale: exp2 later, no mul
      const unsigned short hi = f2bf(qs);
      const unsigned short lo = f2bf(qs - bf2f(hi));
      q_t[gn * 16 + d] = hi;
      q_t[gn * 16 + 8 + d] = lo;
    } else {
      const float ks = v + bk[d - 8];
      const unsigned short hi = f2bf(ks);
      const unsigned short lo = f2bf(ks - bf2f(hi));
      k_th[gn * 8 + d - 8] = hi;
      k_tl[gn * 8 + d - 8] = lo;
    }
  }
}

// ---- v projection via MFMA: V = Wv(bf16) x X(bf16, LDS-staged) + bv ----
__global__ __launch_bounds__(256) void proj_v_kernel(
    const float* __restrict__ x, const unsigned short* __restrict__ wv_bf,
    const float* __restrict__ bv, unsigned short* __restrict__ v)
{
  __shared__ __align__(16) unsigned short xs[64][264];  // [n][k], pad 8
  const int b = blockIdx.y;
  const int n0 = blockIdx.x * 64;
  const int tid = threadIdx.x;
  const int w = tid >> 6, l = tid & 63;
  const int l31 = l & 31, lh = l >> 5;

  // stage: lane l covers n=l, c in [64w, 64w+64), pack 4 -> ds_write_b64
  const float* xb = x + ((size_t)b * C_ + w * 64) * N_ + n0 + l;
  #pragma unroll
  for (int i = 0; i < 64; i += 4) {
    ushort4 pk;
    pk.x = f2bf(xb[(size_t)(i + 0) * N_]);
    pk.y = f2bf(xb[(size_t)(i + 1) * N_]);
    pk.z = f2bf(xb[(size_t)(i + 2) * N_]);
    pk.w = f2bf(xb[(size_t)(i + 3) * N_]);
    *reinterpret_cast<ushort4*>(&xs[l][w * 64 + i]) = pk;
  }
  __syncthreads();

  // wave w: c_out range [64w, 64w+64) x n range [0,64): 2x2 accs of 32x32
  float16 acc[2][2];
  #pragma unroll
  for (int mi = 0; mi < 2; ++mi)
    #pragma unroll
    for (int ni = 0; ni < 2; ++ni)
      #pragma unroll
      for (int r = 0; r < 16; ++r) acc[mi][ni][r] = 0.f;

  for (int ks = 0; ks < 16; ++ks) {
    short8 af[2], bf[2];
    #pragma unroll
    for (int mi = 0; mi < 2; ++mi)
      af[mi] = *reinterpret_cast<const short8*>(
          wv_bf + (w * 64 + mi * 32 + l31) * C_ + ks * 16 + lh * 8);
    #pragma unroll
    for (int ni = 0; ni < 2; ++ni)
      bf[ni] = *reinterpret_cast<const short8*>(&xs[ni * 32 + l31][ks * 16 + lh * 8]);
    #pragma unroll
    for (int mi = 0; mi < 2; ++mi)
      #pragma unroll
      for (int ni = 0; ni < 2; ++ni)
        acc[mi][ni] = __builtin_amdgcn_mfma_f32_32x32x16_bf16(af[mi], bf[ni], acc[mi][ni], 0, 0, 0);
  }

  #pragma unroll
  for (int mi = 0; mi < 2; ++mi)
    #pragma unroll
    for (int r = 0; r < 16; ++r) {
      const int c = w * 64 + mi * 32 + (r & 3) + 8 * (r >> 2) + 4 * lh;
      const float bvc = bv[c];
      #pragma unroll
      for (int ni = 0; ni < 2; ++ni) {
        const int n = n0 + ni * 32 + l31;
        v[((size_t)b * C_ + c) * N_ + n] = f2bf(acc[mi][ni][r] + bvc);
      }
    }
}

// ---- fused attention: QK-MFMA (hi/lo exact) -> exp -> PV-MFMA ----
__global__ __launch_bounds__(512, 4) void attn_kernel(
    const unsigned short* __restrict__ q_t, const unsigned short* __restrict__ k_th,
    const unsigned short* __restrict__ k_tl, const unsigned short* __restrict__ v,
    const float* __restrict__ x, const float* __restrict__ gamma,
    float* __restrict__ out)
{
  __shared__ __align__(16) unsigned short ps[2][TM][PSTRIDE];
  __shared__ float rsp[4][TM];
  __shared__ float rsn[TM];

  const int b = blockIdx.x;           // batch -> XCD affinity
  const int m0 = blockIdx.y * TM;
  const int tid = threadIdx.x;
  const int w = tid >> 6;
  const int l = tid & 63;
  const int l31 = l & 31, lh = l >> 5;
  const int mt = w >> 2, nt = w & 3;  // QK score tile of this wave

  // Q A-frag, loaded once: rows m0+32mt+l31, [qh|ql] selected by lh
  const short8 aq = *reinterpret_cast<const short8*>(
      q_t + ((size_t)b * N_ + m0 + 32 * mt + l31) * 16 + lh * 8);

  // PV: wave w owns c-range [32w, 32w+32)
  const unsigned short* vrow = v + ((size_t)b * C_ + w * 32 + l31) * N_;
  const unsigned short* kbh = k_th + (size_t)b * N_ * 8;
  const unsigned short* kbl = k_tl + (size_t)b * N_ * 8;

  float16 o0, o1;
  float rsum[16];
  #pragma unroll
  for (int r = 0; r < 16; ++r) { o0[r] = 0.f; o1[r] = 0.f; rsum[r] = 0.f; }

  for (int nc = 0; nc < N_ / TN; ++nc) {
    const int n0 = nc * TN;
    const int buf = nc & 1;

    // --- QK: s = (qh+ql).(kh+kl) via two chained MFMAs (log2 domain) ---
    const int nq = n0 + nt * 32 + l31;
    const short8 bh = *reinterpret_cast<const short8*>(kbh + (size_t)nq * 8);
    const short8 bl = *reinterpret_cast<const short8*>(kbl + (size_t)nq * 8);
    float16 s;
    #pragma unroll
    for (int r = 0; r < 16; ++r) s[r] = 0.f;
    s = __builtin_amdgcn_mfma_f32_32x32x16_bf16(aq, bh, s, 0, 0, 0);
    s = __builtin_amdgcn_mfma_f32_32x32x16_bf16(aq, bl, s, 0, 0, 0);

    // --- exp (base-2, q pre-scaled) + bf16 P into LDS ---
    #pragma unroll
    for (int r = 0; r < 16; ++r) {
      const float e = exp2f(s[r]);
      rsum[r] += e;
      const int mrow = 32 * mt + (r & 3) + 8 * (r >> 2) + 4 * lh;
      ps[buf][mrow][nt * 32 + l31] = f2bf(e);
    }
    __syncthreads();

    // --- PV: D[c][m] += V[c][n] . P^T ---
    #pragma unroll
    for (int ks = 0; ks < 8; ++ks) {
      const short8 a = *reinterpret_cast<const short8*>(vrow + n0 + ks * 16 + lh * 8);
      const short8 p0 = *reinterpret_cast<const short8*>(&ps[buf][l31][ks * 16 + lh * 8]);
      const short8 p1 = *reinterpret_cast<const short8*>(&ps[buf][32 + l31][ks * 16 + lh * 8]);
      o0 = __builtin_amdgcn_mfma_f32_32x32x16_bf16(a, p0, o0, 0, 0, 0);
      o1 = __builtin_amdgcn_mfma_f32_32x32x16_bf16(a, p1, o1, 0, 0, 0);
    }
  }

  // --- row sums: reduce over the 32 n-lanes, stash per nt-wave, combine ---
  #pragma unroll
  for (int r = 0; r < 16; ++r) {
    float ss = rsum[r];
    #pragma unroll
    for (int off = 16; off >= 1; off >>= 1) ss += __shfl_xor(ss, off);
    rsum[r] = ss;
  }
  if (l31 == 0) {
    #pragma unroll
    for (int r = 0; r < 16; ++r) {
      const int mrow = 32 * mt + (r & 3) + 8 * (r >> 2) + 4 * lh;
      rsp[nt][mrow] = rsum[r];
    }
  }
  __syncthreads();
  if (tid < TM) rsn[tid] = rsp[0][tid] + rsp[1][tid] + rsp[2][tid] + rsp[3][tid];
  __syncthreads();

  // --- epilogue: out = gamma/rowsum * O + x ---
  const float g = gamma[0];
  const float t0 = g / rsn[l31];
  const float t1 = g / rsn[32 + l31];
  #pragma unroll
  for (int r = 0; r < 16; ++r) {
    const int c = 32 * w + (r & 3) + 8 * (r >> 2) + 4 * lh;
    const size_t i0 = ((size_t)b * C_ + c) * N_ + m0 + l31;
    out[i0]      = fmaf(o0[r], t0, x[i0]);
    out[i0 + 32] = fmaf(o1[r], t1, x[i0 + 32]);
  }
}

}  // namespace

extern "C" void kernel_launch(void* const* d_in, const int* in_sizes, int n_in,
                              void* d_out, int out_size, void* d_ws, size_t ws_size,
                              hipStream_t stream) {
  const float* x     = (const float*)d_in[0];
  const float* wq    = (const float*)d_in[1];
  const float* bq    = (const float*)d_in[2];
  const float* wk    = (const float*)d_in[3];
  const float* bk    = (const float*)d_in[4];
  const float* wv    = (const float*)d_in[5];
  const float* bv    = (const float*)d_in[6];
  const float* gamma = (const float*)d_in[7];
  float* out = (float*)d_out;

  // ws: q_t 1MB | k_th 0.5MB | k_tl 0.5MB | wv_bf 128KB | v 16MB
  char* p = (char*)d_ws;
  unsigned short* q_t   = (unsigned short*)p;                 p += (size_t)B_ * N_ * 16 * 2;
  unsigned short* k_th  = (unsigned short*)p;                 p += (size_t)B_ * N_ * 8 * 2;
  unsigned short* k_tl  = (unsigned short*)p;                 p += (size_t)B_ * N_ * 8 * 2;
  unsigned short* wv_bf = (unsigned short*)p;                 p += (size_t)C_ * C_ * 2;
  unsigned short* v     = (unsigned short*)p;

  prep_kernel<<<dim3(C_ * C_ / 1024), 256, 0, stream>>>(wv, wv_bf);
  proj_qk_kernel<<<dim3(N_ / 64, B_), 256, 0, stream>>>(x, wq, bq, wk, bk, q_t, k_th, k_tl);
  proj_v_kernel<<<dim3(N_ / 64, B_), 256, 0, stream>>>(x, wv_bf, bv, v);
  attn_kernel<<<dim3(B_, N_ / TM), 512, 0, stream>>>(q_t, k_th, k_tl, v, x, gamma, out);
}